// Round 6
// baseline (305.397 us; speedup 1.0000x reference)
//
#include <hip/hip_runtime.h>
#include <hip/hip_bf16.h>

#define HID 128
#define NH  4          // heads
#define FEAT (NH*HID)  // 512 per node per projection
#define NEG_SLOPE 0.2f
#define BN_EPS 1e-5f

typedef __attribute__((ext_vector_type(8))) short bf16x8;   // 8 bf16 = 4 VGPR
typedef __attribute__((ext_vector_type(4))) float f32x4;

// ---------- helpers ----------
__device__ inline ushort f2bf(float f) {     // RNE f32 -> bf16
    unsigned u = __float_as_uint(f);
    return (ushort)((u + 0x7fffu + ((u >> 16) & 1u)) >> 16);
}

// ---------- cast f32 -> bf16 (n % 4 == 0) + zero deg ----------
__global__ __launch_bounds__(256) void cast_bf16_deg(const float* __restrict__ in,
                                                     ushort* __restrict__ out, int n,
                                                     int* __restrict__ deg, int N)
{
    int gid = blockIdx.x * 256 + threadIdx.x;
    if (gid < N) deg[gid] = 0;
    int i = gid * 4;
    if (i >= n) return;
    float4 v = *(const float4*)(in + i);
    ushort4 o = make_ushort4(f2bf(v.x), f2bf(v.y), f2bf(v.z), f2bf(v.w));
    *(ushort4*)(out + i) = o;
}

// ---------- transpose + cast two K x Nc f32 mats -> [Nc][K] bf16 each ----------
__global__ __launch_bounds__(256) void transpose_cast2(const float* __restrict__ in0,
                                                       const float* __restrict__ in1,
                                                       ushort* __restrict__ out0,
                                                       ushort* __restrict__ out1,
                                                       int K, int Nc)
{
    const float* in  = blockIdx.z ? in1 : in0;
    ushort*      out = blockIdx.z ? out1 : out0;
    __shared__ float t[32][33];
    int bk = blockIdx.x * 32, bc = blockIdx.y * 32;
    int r = threadIdx.x >> 3, c4 = (threadIdx.x & 7) * 4;
    float4 v = *(const float4*)(in + (size_t)(bk + r) * Nc + bc + c4);
    t[r][c4 + 0] = v.x; t[r][c4 + 1] = v.y; t[r][c4 + 2] = v.z; t[r][c4 + 3] = v.w;
    __syncthreads();
    ushort4 o;
    o.x = f2bf(t[c4 + 0][r]); o.y = f2bf(t[c4 + 1][r]);
    o.z = f2bf(t[c4 + 2][r]); o.w = f2bf(t[c4 + 3][r]);
    *(ushort4*)(out + (size_t)(bc + r) * K + bk + c4) = o;
}

// ---------- bf16 MFMA GEMM: C[M][Nc] = A[M][K] @ Bt[Nc][K]^T, all bf16 ----------
__global__ __launch_bounds__(256) void gemm_bf16(const ushort* __restrict__ A,
                                                 const ushort* __restrict__ Bt,
                                                 ushort* __restrict__ C,
                                                 int M, int Nc, int K)
{
    __shared__ __align__(16) ushort As[128 * 40];  // row stride 40 (pad 8)
    __shared__ __align__(16) ushort Bs[64 * 40];
    const int bm = blockIdx.x * 128;
    const int bn = blockIdx.y * 64;
    const int tid = threadIdx.x;
    const int wid = tid >> 6, lane = tid & 63;
    const int wr = wid >> 1, wc = wid & 1;
    const int l15 = lane & 15, l4 = lane >> 4;

    f32x4 acc[4][2] = {};

    for (int k0 = 0; k0 < K; k0 += 32) {
        #pragma unroll
        for (int s = 0; s < 2; ++s) {
            int c = tid + s * 256;
            int r = c >> 2, cc = (c & 3) * 8;
            uint4 v = make_uint4(0, 0, 0, 0);
            int gr = bm + r;
            if (gr < M) v = *(const uint4*)(A + (size_t)gr * K + k0 + cc);
            *(uint4*)&As[r * 40 + cc] = v;
        }
        {
            int r = tid >> 2, cc = (tid & 3) * 8;
            uint4 v = *(const uint4*)(Bt + (size_t)(bn + r) * K + k0 + cc);
            *(uint4*)&Bs[r * 40 + cc] = v;
        }
        __syncthreads();
        bf16x8 bfr[2];
        #pragma unroll
        for (int n = 0; n < 2; ++n)
            bfr[n] = *(const bf16x8*)&Bs[(wc * 32 + n * 16 + l15) * 40 + l4 * 8];
        #pragma unroll
        for (int m = 0; m < 4; ++m) {
            bf16x8 afr = *(const bf16x8*)&As[(wr * 64 + m * 16 + l15) * 40 + l4 * 8];
            #pragma unroll
            for (int n = 0; n < 2; ++n)
                acc[m][n] = __builtin_amdgcn_mfma_f32_16x16x32_bf16(afr, bfr[n], acc[m][n], 0, 0, 0);
        }
        __syncthreads();
    }
    #pragma unroll
    for (int m = 0; m < 4; ++m)
        #pragma unroll
        for (int n = 0; n < 2; ++n)
            #pragma unroll
            for (int r = 0; r < 4; ++r) {
                int row = bm + wr * 64 + m * 16 + l4 * 4 + r;
                int col = bn + wc * 32 + n * 16 + l15;
                if (row < M) C[(size_t)row * Nc + col] = f2bf(acc[m][n][r]);
            }
}

// ---------- CSR build ----------
__global__ __launch_bounds__(256) void csr_count(const int* __restrict__ ei,
                                                 int* __restrict__ deg,
                                                 int E, int Etot)
{
    int i = blockIdx.x * 256 + threadIdx.x;
    if (i >= Etot) return;
    int dst = (i < E) ? ei[E + i] : (i - E);
    atomicAdd(&deg[dst], 1);
}

__global__ __launch_bounds__(1024) void scan_rowptr(const int* __restrict__ deg,
                                                    int* __restrict__ rowptr,
                                                    int* __restrict__ cursor,
                                                    int N)
{
    __shared__ int part[1024];
    int t = threadIdx.x;
    int chunk = (N + 1023) / 1024;
    int lo = t * chunk;
    int hi = lo + chunk; if (hi > N) hi = N; if (lo > N) lo = N;
    int s = 0;
    for (int i = lo; i < hi; ++i) s += deg[i];
    part[t] = s;
    __syncthreads();
    for (int off = 1; off < 1024; off <<= 1) {
        int v = (t >= off) ? part[t - off] : 0;
        __syncthreads();
        part[t] += v;
        __syncthreads();
    }
    int base = (t == 0) ? 0 : part[t - 1];
    for (int i = lo; i < hi; ++i) {
        rowptr[i] = base;
        cursor[i] = base;
        base += deg[i];
    }
    if (t == 1023) rowptr[N] = part[1023];
}

__global__ __launch_bounds__(256) void csr_fill(const int* __restrict__ ei,
                                                int* __restrict__ cursor,
                                                int* __restrict__ csr_src,
                                                int* __restrict__ csr_eid,
                                                int E, int Etot)
{
    int i = blockIdx.x * 256 + threadIdx.x;
    if (i >= Etot) return;
    int src, dst;
    if (i < E) { src = ei[i]; dst = ei[E + i]; }
    else       { src = dst = i - E; }
    int pos = atomicAdd(&cursor[dst], 1);
    csr_src[pos] = src;
    csr_eid[pos] = i;
}

// ---------- fused attention: 1 block per dst node, 1 head per wave ----------
// lane covers channels {2*lane, 2*lane+1} of this head's 128.
// Scan edges with online softmax (raw logits -> alpha buf), then finalize
// alpha in-kernel and combine heads via LDS (+bias+BN+ReLU).
__global__ __launch_bounds__(256) void fused_attn(const ushort* __restrict__ xl,
                                                  const ushort* __restrict__ xr,
                                                  const int* __restrict__ rowptr,
                                                  const int* __restrict__ csr_src,
                                                  const int* __restrict__ csr_eid,
                                                  const float* __restrict__ att,
                                                  float* __restrict__ alpha,
                                                  const float* __restrict__ bias,
                                                  const float* __restrict__ g,
                                                  const float* __restrict__ be,
                                                  const float* __restrict__ bm,
                                                  const float* __restrict__ bv,
                                                  ushort* __restrict__ hout, int N)
{
    __shared__ float hsum[NH][HID];
    const int n = blockIdx.x;
    const int head = threadIdx.x >> 6;
    const int lane = threadIdx.x & 63;
    const size_t base = (size_t)head * HID + lane * 2;

    float xr0, xr1, at0, at1;
    {
        unsigned q = *(const unsigned*)(xr + (size_t)n * FEAT + base);
        xr0 = __uint_as_float(q << 16);
        xr1 = __uint_as_float(q & 0xffff0000u);
        float2 a = *(const float2*)(att + base);
        at0 = a.x; at1 = a.y;
    }

    float mrun = -1e30f, den = 0.f, acc0 = 0.f, acc1 = 0.f;
    const int beg = rowptr[n], end = rowptr[n + 1];
    int k = beg;

    for (; k + 3 < end; k += 4) {
        int s0 = csr_src[k],     s1 = csr_src[k + 1];
        int s2 = csr_src[k + 2], s3 = csr_src[k + 3];

        unsigned q0 = *(const unsigned*)(xl + (size_t)s0 * FEAT + base);
        unsigned q1 = *(const unsigned*)(xl + (size_t)s1 * FEAT + base);
        unsigned q2 = *(const unsigned*)(xl + (size_t)s2 * FEAT + base);
        unsigned q3 = *(const unsigned*)(xl + (size_t)s3 * FEAT + base);
        float x0a = __uint_as_float(q0 << 16), x0b = __uint_as_float(q0 & 0xffff0000u);
        float x1a = __uint_as_float(q1 << 16), x1b = __uint_as_float(q1 & 0xffff0000u);
        float x2a = __uint_as_float(q2 << 16), x2b = __uint_as_float(q2 & 0xffff0000u);
        float x3a = __uint_as_float(q3 << 16), x3b = __uint_as_float(q3 & 0xffff0000u);

        float t0a = x0a + xr0; t0a = fmaxf(t0a, NEG_SLOPE * t0a);
        float t0b = x0b + xr1; t0b = fmaxf(t0b, NEG_SLOPE * t0b);
        float t1a = x1a + xr0; t1a = fmaxf(t1a, NEG_SLOPE * t1a);
        float t1b = x1b + xr1; t1b = fmaxf(t1b, NEG_SLOPE * t1b);
        float t2a = x2a + xr0; t2a = fmaxf(t2a, NEG_SLOPE * t2a);
        float t2b = x2b + xr1; t2b = fmaxf(t2b, NEG_SLOPE * t2b);
        float t3a = x3a + xr0; t3a = fmaxf(t3a, NEG_SLOPE * t3a);
        float t3b = x3b + xr1; t3b = fmaxf(t3b, NEG_SLOPE * t3b);
        float l0 = t0a * at0 + t0b * at1;
        float l1 = t1a * at0 + t1b * at1;
        float l2 = t2a * at0 + t2b * at1;
        float l3 = t3a * at0 + t3b * at1;
        #pragma unroll
        for (int off = 1; off < 64; off <<= 1) {
            l0 += __shfl_xor(l0, off, 64);
            l1 += __shfl_xor(l1, off, 64);
            l2 += __shfl_xor(l2, off, 64);
            l3 += __shfl_xor(l3, off, 64);
        }
        if (lane == 0) {
            alpha[(size_t)csr_eid[k]     * NH + head] = l0;
            alpha[(size_t)csr_eid[k + 1] * NH + head] = l1;
            alpha[(size_t)csr_eid[k + 2] * NH + head] = l2;
            alpha[(size_t)csr_eid[k + 3] * NH + head] = l3;
        }
        float bmax = fmaxf(fmaxf(l0, l1), fmaxf(l2, l3));
        if (bmax > mrun) {
            float sc = __expf(mrun - bmax);
            den *= sc; acc0 *= sc; acc1 *= sc;
            mrun = bmax;
        }
        float w0 = __expf(l0 - mrun), w1 = __expf(l1 - mrun);
        float w2 = __expf(l2 - mrun), w3 = __expf(l3 - mrun);
        den += (w0 + w1) + (w2 + w3);
        acc0 += (w0 * x0a + w1 * x1a) + (w2 * x2a + w3 * x3a);
        acc1 += (w0 * x0b + w1 * x1b) + (w2 * x2b + w3 * x3b);
    }

    for (; k < end; ++k) {
        int src = csr_src[k];
        unsigned q = *(const unsigned*)(xl + (size_t)src * FEAT + base);
        float xa = __uint_as_float(q << 16), xb = __uint_as_float(q & 0xffff0000u);
        float ta = xa + xr0; ta = fmaxf(ta, NEG_SLOPE * ta);
        float tb = xb + xr1; tb = fmaxf(tb, NEG_SLOPE * tb);
        float l = ta * at0 + tb * at1;
        #pragma unroll
        for (int off = 1; off < 64; off <<= 1) l += __shfl_xor(l, off, 64);
        if (lane == 0) alpha[(size_t)csr_eid[k] * NH + head] = l;
        if (l > mrun) {
            float sc = __expf(mrun - l);
            den *= sc; acc0 *= sc; acc1 *= sc;
            mrun = l;
        }
        float e = __expf(l - mrun);
        den += e;
        acc0 += e * xa;
        acc1 += e * xb;
    }

    float invden = 1.f / (den + 1e-16f);
    hsum[head][lane * 2]     = acc0 * invden;
    hsum[head][lane * 2 + 1] = acc1 * invden;

    // finalize this row's alphas (raw logits written above by this wave)
    asm volatile("s_waitcnt vmcnt(0)" ::: "memory");
    for (int k2 = beg + lane; k2 < end; k2 += 64) {
        size_t idx = (size_t)csr_eid[k2] * NH + head;
        float raw = alpha[idx];
        alpha[idx] = __expf(raw - mrun) * invden;
    }

    __syncthreads();
    if (threadIdx.x < HID) {
        int c = threadIdx.x;
        float s = (hsum[0][c] + hsum[1][c] + hsum[2][c] + hsum[3][c]) * 0.25f + bias[c];
        float bnv = (s - bm[c]) * rsqrtf(bv[c] + BN_EPS) * g[c] + be[c];
        hout[(size_t)n * HID + c] = f2bf(fmaxf(bnv, 0.f));
    }
}

// ---------- final linear + relu + sigmoid (bf16 h) ----------
__global__ __launch_bounds__(256) void final_lin(const ushort* __restrict__ h,
                                                 const float* __restrict__ W,
                                                 const float* __restrict__ b,
                                                 float* __restrict__ out, int N)
{
    int gw = (blockIdx.x * 256 + threadIdx.x) >> 6;
    int lane = threadIdx.x & 63;
    if (gw >= N) return;
    unsigned q = *(const unsigned*)(h + (size_t)gw * HID + lane * 2);
    float h0 = __uint_as_float(q << 16);
    float h1 = __uint_as_float(q & 0xffff0000u);
    float s = h0 * W[lane * 2] + h1 * W[lane * 2 + 1];
    #pragma unroll
    for (int off = 1; off < 64; off <<= 1) s += __shfl_xor(s, off, 64);
    if (lane == 0) {
        float z = fmaxf(s + b[0], 0.f);
        out[gw] = 1.f / (1.f + expf(-z));
    }
}

extern "C" void kernel_launch(void* const* d_in, const int* in_sizes, int n_in,
                              void* d_out, int out_size, void* d_ws, size_t ws_size,
                              hipStream_t stream)
{
    const float* x    = (const float*)d_in[0];
    const int*   ei   = (const int*)d_in[1];
    const float* Wl1  = (const float*)d_in[2];
    const float* Wr1  = (const float*)d_in[3];
    const float* att1 = (const float*)d_in[4];
    const float* b1   = (const float*)d_in[5];
    const float* Wl2  = (const float*)d_in[6];
    const float* Wr2  = (const float*)d_in[7];
    const float* att2 = (const float*)d_in[8];
    const float* b2   = (const float*)d_in[9];
    const float* g1   = (const float*)d_in[10];
    const float* be1  = (const float*)d_in[11];
    const float* m1   = (const float*)d_in[12];
    const float* v1   = (const float*)d_in[13];
    const float* g2   = (const float*)d_in[14];
    const float* be2  = (const float*)d_in[15];
    const float* m2   = (const float*)d_in[16];
    const float* v2   = (const float*)d_in[17];
    const float* Wlin = (const float*)d_in[18];
    const float* blin = (const float*)d_in[19];

    const int IN_C = 256;
    const int N = in_sizes[0] / IN_C;       // 10000
    const int E = in_sizes[1] / 2;          // 320000
    const int Etot = E + N;                 // with self loops

    float* out    = (float*)d_out;          // [N]
    float* alpha1 = out + N;                // [Etot*NH]
    float* alpha2 = alpha1 + (size_t)Etot * NH;

    // workspace layout (bytes)
    char* wsb = (char*)d_ws;
    ushort* xbf   = (ushort*)wsb;                       wsb += (size_t)N * IN_C * 2;
    ushort* xlbf  = (ushort*)wsb;                       wsb += (size_t)N * FEAT * 2;
    ushort* xrbf  = (ushort*)wsb;                       wsb += (size_t)N * FEAT * 2;
    ushort* hbbf  = (ushort*)wsb;                       wsb += (size_t)N * HID * 2;
    ushort* wt1l  = (ushort*)wsb;                       wsb += (size_t)FEAT * IN_C * 2;
    ushort* wt1r  = (ushort*)wsb;                       wsb += (size_t)FEAT * IN_C * 2;
    ushort* wt2l  = (ushort*)wsb;                       wsb += (size_t)FEAT * HID * 2;
    ushort* wt2r  = (ushort*)wsb;                       wsb += (size_t)FEAT * HID * 2;
    int*    deg    = (int*)wsb;                         wsb += (size_t)N * 4;
    int*    cursor = (int*)wsb;                         wsb += (size_t)N * 4;
    int*    rowptr = (int*)wsb;                         wsb += (size_t)(N + 1) * 4;
    int*    csrsrc = (int*)wsb;                         wsb += (size_t)Etot * 4;
    int*    csreid = (int*)wsb;

    dim3 blk(256);
    dim3 gemm_grid((N + 127) / 128, FEAT / 64);
    int node_wave_blocks = (N + 3) / 4;
    int etot_blocks = (Etot + 255) / 256;

    // ---- casts (+deg zero) ----
    cast_bf16_deg<<<(N * IN_C / 4 + 255) / 256, blk, 0, stream>>>(x, xbf, N * IN_C, deg, N);
    transpose_cast2<<<dim3(IN_C / 32, FEAT / 32, 2), blk, 0, stream>>>(Wl1, Wr1, wt1l, wt1r, IN_C, FEAT);
    transpose_cast2<<<dim3(HID / 32, FEAT / 32, 2), blk, 0, stream>>>(Wl2, Wr2, wt2l, wt2r, HID, FEAT);

    // ---- CSR build (shared by both layers) ----
    csr_count<<<etot_blocks, blk, 0, stream>>>(ei, deg, E, Etot);
    scan_rowptr<<<1, 1024, 0, stream>>>(deg, rowptr, cursor, N);
    csr_fill<<<etot_blocks, blk, 0, stream>>>(ei, cursor, csrsrc, csreid, E, Etot);

    // ================= layer 1 =================
    gemm_bf16<<<gemm_grid, blk, 0, stream>>>(xbf, wt1l, xlbf, N, FEAT, IN_C);
    gemm_bf16<<<gemm_grid, blk, 0, stream>>>(xbf, wt1r, xrbf, N, FEAT, IN_C);
    fused_attn<<<N, blk, 0, stream>>>(xlbf, xrbf, rowptr, csrsrc, csreid,
                                      att1, alpha1, b1, g1, be1, m1, v1, hbbf, N);

    // ================= layer 2 =================
    gemm_bf16<<<gemm_grid, blk, 0, stream>>>(hbbf, wt2l, xlbf, N, FEAT, HID);
    gemm_bf16<<<gemm_grid, blk, 0, stream>>>(hbbf, wt2r, xrbf, N, FEAT, HID);
    fused_attn<<<N, blk, 0, stream>>>(xlbf, xrbf, rowptr, csrsrc, csreid,
                                      att2, alpha2, b2, g2, be2, m2, v2, hbbf, N);

    // ================= head =================
    final_lin<<<node_wave_blocks, blk, 0, stream>>>(hbbf, Wlin, blin, out, N);
}

// Round 7
// 290.443 us; speedup vs baseline: 1.0515x; 1.0515x over previous
//
#include <hip/hip_runtime.h>
#include <hip/hip_bf16.h>

#define HID 128
#define NH  4          // heads
#define FEAT (NH*HID)  // 512 per node per projection
#define NEG_SLOPE 0.2f
#define BN_EPS 1e-5f

typedef __attribute__((ext_vector_type(8))) short bf16x8;   // 8 bf16 = 4 VGPR
typedef __attribute__((ext_vector_type(4))) float f32x4;

// ---------- helpers ----------
__device__ inline ushort f2bf(float f) {     // RNE f32 -> bf16
    unsigned u = __float_as_uint(f);
    return (ushort)((u + 0x7fffu + ((u >> 16) & 1u)) >> 16);
}
__device__ inline void ubf8(const ushort* p, float* o) {  // 8 bf16 -> 8 f32
    uint4 q = *(const uint4*)p;
    o[0] = __uint_as_float(q.x << 16); o[1] = __uint_as_float(q.x & 0xffff0000u);
    o[2] = __uint_as_float(q.y << 16); o[3] = __uint_as_float(q.y & 0xffff0000u);
    o[4] = __uint_as_float(q.z << 16); o[5] = __uint_as_float(q.z & 0xffff0000u);
    o[6] = __uint_as_float(q.w << 16); o[7] = __uint_as_float(q.w & 0xffff0000u);
}

// ---------- cast f32 -> bf16 (n % 4 == 0) + zero deg ----------
__global__ __launch_bounds__(256) void cast_bf16_deg(const float* __restrict__ in,
                                                     ushort* __restrict__ out, int n,
                                                     int* __restrict__ deg, int N)
{
    int gid = blockIdx.x * 256 + threadIdx.x;
    if (gid < N) deg[gid] = 0;
    int i = gid * 4;
    if (i >= n) return;
    float4 v = *(const float4*)(in + i);
    ushort4 o = make_ushort4(f2bf(v.x), f2bf(v.y), f2bf(v.z), f2bf(v.w));
    *(ushort4*)(out + i) = o;
}

// ---------- transpose + cast two K x Nc f32 mats -> [Nc][K] bf16 each ----------
__global__ __launch_bounds__(256) void transpose_cast2(const float* __restrict__ in0,
                                                       const float* __restrict__ in1,
                                                       ushort* __restrict__ out0,
                                                       ushort* __restrict__ out1,
                                                       int K, int Nc)
{
    const float* in  = blockIdx.z ? in1 : in0;
    ushort*      out = blockIdx.z ? out1 : out0;
    __shared__ float t[32][33];
    int bk = blockIdx.x * 32, bc = blockIdx.y * 32;
    int r = threadIdx.x >> 3, c4 = (threadIdx.x & 7) * 4;
    float4 v = *(const float4*)(in + (size_t)(bk + r) * Nc + bc + c4);
    t[r][c4 + 0] = v.x; t[r][c4 + 1] = v.y; t[r][c4 + 2] = v.z; t[r][c4 + 3] = v.w;
    __syncthreads();
    ushort4 o;
    o.x = f2bf(t[c4 + 0][r]); o.y = f2bf(t[c4 + 1][r]);
    o.z = f2bf(t[c4 + 2][r]); o.w = f2bf(t[c4 + 3][r]);
    *(ushort4*)(out + (size_t)(bc + r) * K + bk + c4) = o;
}

// ---------- bf16 MFMA GEMM: C[M][Nc] = A[M][K] @ Bt[Nc][K]^T, all bf16 ----------
__global__ __launch_bounds__(256) void gemm_bf16(const ushort* __restrict__ A,
                                                 const ushort* __restrict__ Bt,
                                                 ushort* __restrict__ C,
                                                 int M, int Nc, int K)
{
    __shared__ __align__(16) ushort As[128 * 40];  // row stride 40 (pad 8)
    __shared__ __align__(16) ushort Bs[64 * 40];
    const int bm = blockIdx.x * 128;
    const int bn = blockIdx.y * 64;
    const int tid = threadIdx.x;
    const int wid = tid >> 6, lane = tid & 63;
    const int wr = wid >> 1, wc = wid & 1;
    const int l15 = lane & 15, l4 = lane >> 4;

    f32x4 acc[4][2] = {};

    for (int k0 = 0; k0 < K; k0 += 32) {
        #pragma unroll
        for (int s = 0; s < 2; ++s) {
            int c = tid + s * 256;
            int r = c >> 2, cc = (c & 3) * 8;
            uint4 v = make_uint4(0, 0, 0, 0);
            int gr = bm + r;
            if (gr < M) v = *(const uint4*)(A + (size_t)gr * K + k0 + cc);
            *(uint4*)&As[r * 40 + cc] = v;
        }
        {
            int r = tid >> 2, cc = (tid & 3) * 8;
            uint4 v = *(const uint4*)(Bt + (size_t)(bn + r) * K + k0 + cc);
            *(uint4*)&Bs[r * 40 + cc] = v;
        }
        __syncthreads();
        bf16x8 bfr[2];
        #pragma unroll
        for (int n = 0; n < 2; ++n)
            bfr[n] = *(const bf16x8*)&Bs[(wc * 32 + n * 16 + l15) * 40 + l4 * 8];
        #pragma unroll
        for (int m = 0; m < 4; ++m) {
            bf16x8 afr = *(const bf16x8*)&As[(wr * 64 + m * 16 + l15) * 40 + l4 * 8];
            #pragma unroll
            for (int n = 0; n < 2; ++n)
                acc[m][n] = __builtin_amdgcn_mfma_f32_16x16x32_bf16(afr, bfr[n], acc[m][n], 0, 0, 0);
        }
        __syncthreads();
    }
    #pragma unroll
    for (int m = 0; m < 4; ++m)
        #pragma unroll
        for (int n = 0; n < 2; ++n)
            #pragma unroll
            for (int r = 0; r < 4; ++r) {
                int row = bm + wr * 64 + m * 16 + l4 * 4 + r;
                int col = bn + wc * 32 + n * 16 + l15;
                if (row < M) C[(size_t)row * Nc + col] = f2bf(acc[m][n][r]);
            }
}

// ---------- CSR build ----------
__global__ __launch_bounds__(256) void csr_count(const int* __restrict__ ei,
                                                 int* __restrict__ deg,
                                                 int E, int Etot)
{
    int i = blockIdx.x * 256 + threadIdx.x;
    if (i >= Etot) return;
    int dst = (i < E) ? ei[E + i] : (i - E);
    atomicAdd(&deg[dst], 1);
}

__global__ __launch_bounds__(1024) void scan_rowptr(const int* __restrict__ deg,
                                                    int* __restrict__ rowptr,
                                                    int* __restrict__ cursor,
                                                    int N)
{
    __shared__ int part[1024];
    int t = threadIdx.x;
    int chunk = (N + 1023) / 1024;
    int lo = t * chunk;
    int hi = lo + chunk; if (hi > N) hi = N; if (lo > N) lo = N;
    int s = 0;
    for (int i = lo; i < hi; ++i) s += deg[i];
    part[t] = s;
    __syncthreads();
    for (int off = 1; off < 1024; off <<= 1) {
        int v = (t >= off) ? part[t - off] : 0;
        __syncthreads();
        part[t] += v;
        __syncthreads();
    }
    int base = (t == 0) ? 0 : part[t - 1];
    for (int i = lo; i < hi; ++i) {
        rowptr[i] = base;
        cursor[i] = base;
        base += deg[i];
    }
    if (t == 1023) rowptr[N] = part[1023];
}

__global__ __launch_bounds__(256) void csr_fill(const int* __restrict__ ei,
                                                int* __restrict__ cursor,
                                                int* __restrict__ csr_src,
                                                int* __restrict__ csr_eid,
                                                int E, int Etot)
{
    int i = blockIdx.x * 256 + threadIdx.x;
    if (i >= Etot) return;
    int src, dst;
    if (i < E) { src = ei[i]; dst = ei[E + i]; }
    else       { src = dst = i - E; }
    int pos = atomicAdd(&cursor[dst], 1);
    csr_src[pos] = src;
    csr_eid[pos] = i;
}

// ---------- fused attention: 1 block (4 waves) per dst node ----------
// Each wave owns a quarter of the node's edge list with R5's per-edge layout
// (head = lane>>4, sub = lane&15, 8 channels = 16B per lane). Partial online
// softmax states combined via LDS; alpha finalized in-kernel (per-wave own
// logit writes); head-mean + bias + BN + ReLU fused at the end.
__global__ __launch_bounds__(256) void fused_attn(const ushort* __restrict__ xl,
                                                  const ushort* __restrict__ xr,
                                                  const int* __restrict__ rowptr,
                                                  const int* __restrict__ csr_src,
                                                  const int* __restrict__ csr_eid,
                                                  const float* __restrict__ att,
                                                  float* __restrict__ alpha,
                                                  const float* __restrict__ bias,
                                                  const float* __restrict__ g,
                                                  const float* __restrict__ be,
                                                  const float* __restrict__ bmn,
                                                  const float* __restrict__ bvr,
                                                  ushort* __restrict__ hout, int N)
{
    __shared__ float accs[4][8][64];   // [wave][j][lane] lane-major: conflict-free
    __shared__ float smd[4][2][NH];    // [wave][m|den][head]
    const int n = blockIdx.x;
    const int wid = threadIdx.x >> 6;
    const int lane = threadIdx.x & 63;
    const int head = lane >> 4, sub = lane & 15;
    const size_t foff = (size_t)head * HID + sub * 8;

    float xrv[8], atv[8];
    ubf8(xr + (size_t)n * FEAT + foff, xrv);
    {
        const float4* a4 = (const float4*)(att + foff);
        float4 t0 = a4[0], t1 = a4[1];
        atv[0]=t0.x; atv[1]=t0.y; atv[2]=t0.z; atv[3]=t0.w;
        atv[4]=t1.x; atv[5]=t1.y; atv[6]=t1.z; atv[7]=t1.w;
    }

    const int beg = rowptr[n], end = rowptr[n + 1];
    const int quarter = (end - beg + 3) >> 2;
    int mybeg = beg + wid * quarter;
    int myend = mybeg + quarter;
    if (myend > end) myend = end;
    if (mybeg > end) mybeg = end;

    float mrun = -1e30f, den = 0.f, acc[8] = {};
    int k = mybeg;

    for (; k + 3 < myend; k += 4) {
        int s0 = csr_src[k],     s1 = csr_src[k + 1];
        int s2 = csr_src[k + 2], s3 = csr_src[k + 3];
        int e0 = csr_eid[k],     e1 = csr_eid[k + 1];
        int e2 = csr_eid[k + 2], e3 = csr_eid[k + 3];

        float xv0[8], xv1[8], xv2[8], xv3[8];
        ubf8(xl + (size_t)s0 * FEAT + foff, xv0);
        ubf8(xl + (size_t)s1 * FEAT + foff, xv1);
        ubf8(xl + (size_t)s2 * FEAT + foff, xv2);
        ubf8(xl + (size_t)s3 * FEAT + foff, xv3);

        float l0 = 0.f, l1 = 0.f, l2 = 0.f, l3 = 0.f;
        #pragma unroll
        for (int j = 0; j < 8; ++j) {
            float t0 = xv0[j] + xrv[j]; t0 = fmaxf(t0, NEG_SLOPE * t0);
            float t1 = xv1[j] + xrv[j]; t1 = fmaxf(t1, NEG_SLOPE * t1);
            float t2 = xv2[j] + xrv[j]; t2 = fmaxf(t2, NEG_SLOPE * t2);
            float t3 = xv3[j] + xrv[j]; t3 = fmaxf(t3, NEG_SLOPE * t3);
            l0 += t0 * atv[j]; l1 += t1 * atv[j];
            l2 += t2 * atv[j]; l3 += t3 * atv[j];
        }
        #pragma unroll
        for (int off = 1; off < 16; off <<= 1) {
            l0 += __shfl_xor(l0, off, 64);
            l1 += __shfl_xor(l1, off, 64);
            l2 += __shfl_xor(l2, off, 64);
            l3 += __shfl_xor(l3, off, 64);
        }
        if (sub == 0) {
            alpha[(size_t)e0 * NH + head] = l0;
            alpha[(size_t)e1 * NH + head] = l1;
            alpha[(size_t)e2 * NH + head] = l2;
            alpha[(size_t)e3 * NH + head] = l3;
        }
        float bmax = fmaxf(fmaxf(l0, l1), fmaxf(l2, l3));
        if (bmax > mrun) {
            float sc = __expf(mrun - bmax);
            den *= sc;
            #pragma unroll
            for (int j = 0; j < 8; ++j) acc[j] *= sc;
            mrun = bmax;
        }
        float w0 = __expf(l0 - mrun), w1 = __expf(l1 - mrun);
        float w2 = __expf(l2 - mrun), w3 = __expf(l3 - mrun);
        den += (w0 + w1) + (w2 + w3);
        #pragma unroll
        for (int j = 0; j < 8; ++j)
            acc[j] += (w0 * xv0[j] + w1 * xv1[j]) + (w2 * xv2[j] + w3 * xv3[j]);
    }

    for (; k < myend; ++k) {
        int src = csr_src[k];
        int eid = csr_eid[k];
        float xv[8];
        ubf8(xl + (size_t)src * FEAT + foff, xv);
        float s = 0.f;
        #pragma unroll
        for (int j = 0; j < 8; ++j) {
            float t = xv[j] + xrv[j];
            t = fmaxf(t, NEG_SLOPE * t);
            s += t * atv[j];
        }
        #pragma unroll
        for (int off = 1; off < 16; off <<= 1) s += __shfl_xor(s, off, 64);
        if (sub == 0) alpha[(size_t)eid * NH + head] = s;
        if (s > mrun) {
            float sc = __expf(mrun - s);
            den *= sc;
            #pragma unroll
            for (int j = 0; j < 8; ++j) acc[j] *= sc;
            mrun = s;
        }
        float e = __expf(s - mrun);
        den += e;
        #pragma unroll
        for (int j = 0; j < 8; ++j) acc[j] += e * xv[j];
    }

    // ---- combine 4 partial states via LDS ----
    #pragma unroll
    for (int j = 0; j < 8; ++j) accs[wid][j][lane] = acc[j];
    if (sub == 0) { smd[wid][0][head] = mrun; smd[wid][1][head] = den; }
    __syncthreads();

    float m0 = smd[0][0][head], m1 = smd[1][0][head];
    float m2 = smd[2][0][head], m3 = smd[3][0][head];
    float mg = fmaxf(fmaxf(m0, m1), fmaxf(m2, m3));
    float s0 = __expf(m0 - mg), s1 = __expf(m1 - mg);
    float s2 = __expf(m2 - mg), s3 = __expf(m3 - mg);
    float deng = smd[0][1][head] * s0 + smd[1][1][head] * s1 +
                 smd[2][1][head] * s2 + smd[3][1][head] * s3;
    float inv = 1.f / (deng + 1e-16f);

    float t8[8];
    #pragma unroll
    for (int j = 0; j < 8; ++j) {
        float t = (accs[0][j][lane] * s0 + accs[1][j][lane] * s1 +
                   accs[2][j][lane] * s2 + accs[3][j][lane] * s3) * inv;
        t += __shfl_xor(t, 16, 64);
        t += __shfl_xor(t, 32, 64);
        t8[j] = t;
    }
    if (wid == 0 && head == 0) {
        uint4 o;
        unsigned w[4];
        #pragma unroll
        for (int q = 0; q < 4; ++q) {
            float r0, r1;
            {
                int c = sub * 8 + 2 * q;
                float s = t8[2 * q] * 0.25f + bias[c];
                float bn = (s - bmn[c]) * rsqrtf(bvr[c] + BN_EPS) * g[c] + be[c];
                r0 = fmaxf(bn, 0.f);
            }
            {
                int c = sub * 8 + 2 * q + 1;
                float s = t8[2 * q + 1] * 0.25f + bias[c];
                float bn = (s - bmn[c]) * rsqrtf(bvr[c] + BN_EPS) * g[c] + be[c];
                r1 = fmaxf(bn, 0.f);
            }
            w[q] = (unsigned)f2bf(r0) | ((unsigned)f2bf(r1) << 16);
        }
        o.x = w[0]; o.y = w[1]; o.z = w[2]; o.w = w[3];
        *(uint4*)(hout + (size_t)n * HID + sub * 8) = o;
    }

    // ---- finalize this wave's raw logits with global (mg, inv) ----
    // each 16-lane head-group rewrites its head's entries of the wave's range
    asm volatile("s_waitcnt vmcnt(0)" ::: "memory");
    for (int k2 = mybeg + sub; k2 < myend; k2 += 16) {
        size_t idx = (size_t)csr_eid[k2] * NH + head;
        alpha[idx] = __expf(alpha[idx] - mg) * inv;
    }
}

// ---------- final linear + relu + sigmoid (bf16 h) ----------
__global__ __launch_bounds__(256) void final_lin(const ushort* __restrict__ h,
                                                 const float* __restrict__ W,
                                                 const float* __restrict__ b,
                                                 float* __restrict__ out, int N)
{
    int gw = (blockIdx.x * 256 + threadIdx.x) >> 6;
    int lane = threadIdx.x & 63;
    if (gw >= N) return;
    unsigned q = *(const unsigned*)(h + (size_t)gw * HID + lane * 2);
    float h0 = __uint_as_float(q << 16);
    float h1 = __uint_as_float(q & 0xffff0000u);
    float s = h0 * W[lane * 2] + h1 * W[lane * 2 + 1];
    #pragma unroll
    for (int off = 1; off < 64; off <<= 1) s += __shfl_xor(s, off, 64);
    if (lane == 0) {
        float z = fmaxf(s + b[0], 0.f);
        out[gw] = 1.f / (1.f + expf(-z));
    }
}

extern "C" void kernel_launch(void* const* d_in, const int* in_sizes, int n_in,
                              void* d_out, int out_size, void* d_ws, size_t ws_size,
                              hipStream_t stream)
{
    const float* x    = (const float*)d_in[0];
    const int*   ei   = (const int*)d_in[1];
    const float* Wl1  = (const float*)d_in[2];
    const float* Wr1  = (const float*)d_in[3];
    const float* att1 = (const float*)d_in[4];
    const float* b1   = (const float*)d_in[5];
    const float* Wl2  = (const float*)d_in[6];
    const float* Wr2  = (const float*)d_in[7];
    const float* att2 = (const float*)d_in[8];
    const float* b2   = (const float*)d_in[9];
    const float* g1   = (const float*)d_in[10];
    const float* be1  = (const float*)d_in[11];
    const float* m1   = (const float*)d_in[12];
    const float* v1   = (const float*)d_in[13];
    const float* g2   = (const float*)d_in[14];
    const float* be2  = (const float*)d_in[15];
    const float* m2   = (const float*)d_in[16];
    const float* v2   = (const float*)d_in[17];
    const float* Wlin = (const float*)d_in[18];
    const float* blin = (const float*)d_in[19];

    const int IN_C = 256;
    const int N = in_sizes[0] / IN_C;       // 10000
    const int E = in_sizes[1] / 2;          // 320000
    const int Etot = E + N;                 // with self loops

    float* out    = (float*)d_out;          // [N]
    float* alpha1 = out + N;                // [Etot*NH]
    float* alpha2 = alpha1 + (size_t)Etot * NH;

    // workspace layout (bytes)
    char* wsb = (char*)d_ws;
    ushort* xbf   = (ushort*)wsb;                       wsb += (size_t)N * IN_C * 2;
    ushort* xlbf  = (ushort*)wsb;                       wsb += (size_t)N * FEAT * 2;
    ushort* xrbf  = (ushort*)wsb;                       wsb += (size_t)N * FEAT * 2;
    ushort* hbbf  = (ushort*)wsb;                       wsb += (size_t)N * HID * 2;
    ushort* wt1l  = (ushort*)wsb;                       wsb += (size_t)FEAT * IN_C * 2;
    ushort* wt1r  = (ushort*)wsb;                       wsb += (size_t)FEAT * IN_C * 2;
    ushort* wt2l  = (ushort*)wsb;                       wsb += (size_t)FEAT * HID * 2;
    ushort* wt2r  = (ushort*)wsb;                       wsb += (size_t)FEAT * HID * 2;
    int*    deg    = (int*)wsb;                         wsb += (size_t)N * 4;
    int*    cursor = (int*)wsb;                         wsb += (size_t)N * 4;
    int*    rowptr = (int*)wsb;                         wsb += (size_t)(N + 1) * 4;
    int*    csrsrc = (int*)wsb;                         wsb += (size_t)Etot * 4;
    int*    csreid = (int*)wsb;

    dim3 blk(256);
    dim3 gemm_grid((N + 127) / 128, FEAT / 64);
    int node_wave_blocks = (N + 3) / 4;
    int etot_blocks = (Etot + 255) / 256;

    // ---- casts (+deg zero) ----
    cast_bf16_deg<<<(N * IN_C / 4 + 255) / 256, blk, 0, stream>>>(x, xbf, N * IN_C, deg, N);
    transpose_cast2<<<dim3(IN_C / 32, FEAT / 32, 2), blk, 0, stream>>>(Wl1, Wr1, wt1l, wt1r, IN_C, FEAT);
    transpose_cast2<<<dim3(HID / 32, FEAT / 32, 2), blk, 0, stream>>>(Wl2, Wr2, wt2l, wt2r, HID, FEAT);

    // ---- CSR build (shared by both layers) ----
    csr_count<<<etot_blocks, blk, 0, stream>>>(ei, deg, E, Etot);
    scan_rowptr<<<1, 1024, 0, stream>>>(deg, rowptr, cursor, N);
    csr_fill<<<etot_blocks, blk, 0, stream>>>(ei, cursor, csrsrc, csreid, E, Etot);

    // ================= layer 1 =================
    gemm_bf16<<<gemm_grid, blk, 0, stream>>>(xbf, wt1l, xlbf, N, FEAT, IN_C);
    gemm_bf16<<<gemm_grid, blk, 0, stream>>>(xbf, wt1r, xrbf, N, FEAT, IN_C);
    fused_attn<<<N, blk, 0, stream>>>(xlbf, xrbf, rowptr, csrsrc, csreid,
                                      att1, alpha1, b1, g1, be1, m1, v1, hbbf, N);

    // ================= layer 2 =================
    gemm_bf16<<<gemm_grid, blk, 0, stream>>>(hbbf, wt2l, xlbf, N, FEAT, HID);
    gemm_bf16<<<gemm_grid, blk, 0, stream>>>(hbbf, wt2r, xrbf, N, FEAT, HID);
    fused_attn<<<N, blk, 0, stream>>>(xlbf, xrbf, rowptr, csrsrc, csreid,
                                      att2, alpha2, b2, g2, be2, m2, v2, hbbf, N);

    // ================= head =================
    final_lin<<<node_wave_blocks, blk, 0, stream>>>(hbbf, Wlin, blin, out, N);
}

// Round 8
// 248.400 us; speedup vs baseline: 1.2295x; 1.1693x over previous
//
#include <hip/hip_runtime.h>
#include <hip/hip_bf16.h>

#define HID 128
#define NH  4          // heads
#define FEAT (NH*HID)  // 512 per node per projection
#define F2   (2*FEAT)  // xl|xr packed row stride = 1024
#define NEG_SLOPE 0.2f
#define BN_EPS 1e-5f

typedef __attribute__((ext_vector_type(8))) short bf16x8;   // 8 bf16 = 4 VGPR
typedef __attribute__((ext_vector_type(4))) float f32x4;

// ---------- helpers ----------
__device__ inline ushort f2bf(float f) {     // RNE f32 -> bf16
    unsigned u = __float_as_uint(f);
    return (ushort)((u + 0x7fffu + ((u >> 16) & 1u)) >> 16);
}
__device__ inline void ubf8(const ushort* p, float* o) {  // 8 bf16 -> 8 f32
    uint4 q = *(const uint4*)p;
    o[0] = __uint_as_float(q.x << 16); o[1] = __uint_as_float(q.x & 0xffff0000u);
    o[2] = __uint_as_float(q.y << 16); o[3] = __uint_as_float(q.y & 0xffff0000u);
    o[4] = __uint_as_float(q.z << 16); o[5] = __uint_as_float(q.z & 0xffff0000u);
    o[6] = __uint_as_float(q.w << 16); o[7] = __uint_as_float(q.w & 0xffff0000u);
}

// ---------- cast f32 -> bf16 (n % 4 == 0) + zero deg ----------
__global__ __launch_bounds__(256) void cast_bf16_deg(const float* __restrict__ in,
                                                     ushort* __restrict__ out, int n,
                                                     int* __restrict__ deg, int N)
{
    int gid = blockIdx.x * 256 + threadIdx.x;
    if (gid < N) deg[gid] = 0;
    int i = gid * 4;
    if (i >= n) return;
    float4 v = *(const float4*)(in + i);
    ushort4 o = make_ushort4(f2bf(v.x), f2bf(v.y), f2bf(v.z), f2bf(v.w));
    *(ushort4*)(out + i) = o;
}

// ---------- transpose + cast two K x Nc f32 mats -> [Nc][K] bf16 each ----------
__global__ __launch_bounds__(256) void transpose_cast2(const float* __restrict__ in0,
                                                       const float* __restrict__ in1,
                                                       ushort* __restrict__ out0,
                                                       ushort* __restrict__ out1,
                                                       int K, int Nc)
{
    const float* in  = blockIdx.z ? in1 : in0;
    ushort*      out = blockIdx.z ? out1 : out0;
    __shared__ float t[32][33];
    int bk = blockIdx.x * 32, bc = blockIdx.y * 32;
    int r = threadIdx.x >> 3, c4 = (threadIdx.x & 7) * 4;
    float4 v = *(const float4*)(in + (size_t)(bk + r) * Nc + bc + c4);
    t[r][c4 + 0] = v.x; t[r][c4 + 1] = v.y; t[r][c4 + 2] = v.z; t[r][c4 + 3] = v.w;
    __syncthreads();
    ushort4 o;
    o.x = f2bf(t[c4 + 0][r]); o.y = f2bf(t[c4 + 1][r]);
    o.z = f2bf(t[c4 + 2][r]); o.w = f2bf(t[c4 + 3][r]);
    *(ushort4*)(out + (size_t)(bc + r) * K + bk + c4) = o;
}

// ---------- bf16 MFMA GEMM: C[M][Nc] = A[M][K] @ Bt[Nc][K]^T ----------
// 128x128 tile, BK=32, 256 threads = 4 waves (2x2), per wave 4x4 frags 16x16.
__global__ __launch_bounds__(256) void gemm_bf16(const ushort* __restrict__ A,
                                                 const ushort* __restrict__ Bt,
                                                 ushort* __restrict__ C,
                                                 int M, int Nc, int K)
{
    __shared__ __align__(16) ushort As[128 * 40];  // row stride 40 (pad 8)
    __shared__ __align__(16) ushort Bs[128 * 40];
    const int bm = blockIdx.x * 128;
    const int bn = blockIdx.y * 128;
    const int tid = threadIdx.x;
    const int wid = tid >> 6, lane = tid & 63;
    const int wr = wid >> 1, wc = wid & 1;
    const int l15 = lane & 15, l4 = lane >> 4;

    f32x4 acc[4][4] = {};

    for (int k0 = 0; k0 < K; k0 += 32) {
        #pragma unroll
        for (int s = 0; s < 2; ++s) {               // A,B: 512 chunks of 16B each
            int c = tid + s * 256;
            int r = c >> 2, cc = (c & 3) * 8;
            uint4 v = make_uint4(0, 0, 0, 0);
            int gr = bm + r;
            if (gr < M) v = *(const uint4*)(A + (size_t)gr * K + k0 + cc);
            *(uint4*)&As[r * 40 + cc] = v;
            uint4 w = *(const uint4*)(Bt + (size_t)(bn + r) * K + k0 + cc);
            *(uint4*)&Bs[r * 40 + cc] = w;
        }
        __syncthreads();
        bf16x8 bfr[4];
        #pragma unroll
        for (int n = 0; n < 4; ++n)
            bfr[n] = *(const bf16x8*)&Bs[(wc * 64 + n * 16 + l15) * 40 + l4 * 8];
        #pragma unroll
        for (int m = 0; m < 4; ++m) {
            bf16x8 afr = *(const bf16x8*)&As[(wr * 64 + m * 16 + l15) * 40 + l4 * 8];
            #pragma unroll
            for (int n = 0; n < 4; ++n)
                acc[m][n] = __builtin_amdgcn_mfma_f32_16x16x32_bf16(afr, bfr[n], acc[m][n], 0, 0, 0);
        }
        __syncthreads();
    }
    #pragma unroll
    for (int m = 0; m < 4; ++m)
        #pragma unroll
        for (int n = 0; n < 4; ++n)
            #pragma unroll
            for (int r = 0; r < 4; ++r) {
                int row = bm + wr * 64 + m * 16 + l4 * 4 + r;
                int col = bn + wc * 64 + n * 16 + l15;
                if (row < M) C[(size_t)row * Nc + col] = f2bf(acc[m][n][r]);
            }
}

// ---------- CSR build ----------
__global__ __launch_bounds__(256) void csr_count(const int* __restrict__ ei,
                                                 int* __restrict__ deg,
                                                 int E, int Etot)
{
    int i = blockIdx.x * 256 + threadIdx.x;
    if (i >= Etot) return;
    int dst = (i < E) ? ei[E + i] : (i - E);
    atomicAdd(&deg[dst], 1);
}

__global__ __launch_bounds__(1024) void scan_rowptr(const int* __restrict__ deg,
                                                    int* __restrict__ rowptr,
                                                    int* __restrict__ cursor,
                                                    int N)
{
    __shared__ int part[1024];
    int t = threadIdx.x;
    int chunk = (N + 1023) / 1024;
    int lo = t * chunk;
    int hi = lo + chunk; if (hi > N) hi = N; if (lo > N) lo = N;
    int s = 0;
    for (int i = lo; i < hi; ++i) s += deg[i];
    part[t] = s;
    __syncthreads();
    for (int off = 1; off < 1024; off <<= 1) {
        int v = (t >= off) ? part[t - off] : 0;
        __syncthreads();
        part[t] += v;
        __syncthreads();
    }
    int base = (t == 0) ? 0 : part[t - 1];
    for (int i = lo; i < hi; ++i) {
        rowptr[i] = base;
        cursor[i] = base;
        base += deg[i];
    }
    if (t == 1023) rowptr[N] = part[1023];
}

__global__ __launch_bounds__(256) void csr_fill(const int* __restrict__ ei,
                                                int* __restrict__ cursor,
                                                int* __restrict__ csr_src,
                                                int* __restrict__ csr_eid,
                                                int E, int Etot)
{
    int i = blockIdx.x * 256 + threadIdx.x;
    if (i >= Etot) return;
    int src, dst;
    if (i < E) { src = ei[i]; dst = ei[E + i]; }
    else       { src = dst = i - E; }
    int pos = atomicAdd(&cursor[dst], 1);
    csr_src[pos] = src;
    csr_eid[pos] = i;
}

// ---------- fused per-dst attention (R5 geometry) + in-kernel alpha finalize ----------
// One wave per node; head = lane>>4, sub = lane&15 covers 8 channels (16B/lane).
// xlxr rows are [xl(512) | xr(512)] packed, stride 1024.
// FINAL=false: write h (bf16) for next layer. FINAL=true: fuse h@Wlin+blin -> relu -> sigmoid -> out.
template <bool FINAL>
__global__ __launch_bounds__(256) void fused_attn(const ushort* __restrict__ xlxr,
                                                  const int* __restrict__ rowptr,
                                                  const int* __restrict__ csr_src,
                                                  const int* __restrict__ csr_eid,
                                                  const float* __restrict__ att,
                                                  float* __restrict__ alpha,
                                                  const float* __restrict__ bias,
                                                  const float* __restrict__ g,
                                                  const float* __restrict__ be,
                                                  const float* __restrict__ bmn,
                                                  const float* __restrict__ bvr,
                                                  ushort* __restrict__ hout,
                                                  const float* __restrict__ Wlin,
                                                  const float* __restrict__ blin,
                                                  float* __restrict__ out, int N)
{
    int n = (blockIdx.x * 256 + threadIdx.x) >> 6;
    int lane = threadIdx.x & 63;
    if (n >= N) return;
    int head = lane >> 4, sub = lane & 15;
    const size_t foff = (size_t)head * HID + sub * 8;

    float xrv[8], atv[8];
    ubf8(xlxr + (size_t)n * F2 + FEAT + foff, xrv);
    {
        const float4* a4 = (const float4*)(att + foff);
        float4 t0 = a4[0], t1 = a4[1];
        atv[0]=t0.x; atv[1]=t0.y; atv[2]=t0.z; atv[3]=t0.w;
        atv[4]=t1.x; atv[5]=t1.y; atv[6]=t1.z; atv[7]=t1.w;
    }

    float mrun = -1e30f, den = 0.f, acc[8] = {};
    const int beg = rowptr[n], end = rowptr[n + 1];
    int k = beg;

    for (; k + 3 < end; k += 4) {
        int s0 = csr_src[k],     s1 = csr_src[k + 1];
        int s2 = csr_src[k + 2], s3 = csr_src[k + 3];
        int e0 = csr_eid[k],     e1 = csr_eid[k + 1];
        int e2 = csr_eid[k + 2], e3 = csr_eid[k + 3];

        float xv0[8], xv1[8], xv2[8], xv3[8];
        ubf8(xlxr + (size_t)s0 * F2 + foff, xv0);
        ubf8(xlxr + (size_t)s1 * F2 + foff, xv1);
        ubf8(xlxr + (size_t)s2 * F2 + foff, xv2);
        ubf8(xlxr + (size_t)s3 * F2 + foff, xv3);

        float l0 = 0.f, l1 = 0.f, l2 = 0.f, l3 = 0.f;
        #pragma unroll
        for (int j = 0; j < 8; ++j) {
            float t0 = xv0[j] + xrv[j]; t0 = fmaxf(t0, NEG_SLOPE * t0);
            float t1 = xv1[j] + xrv[j]; t1 = fmaxf(t1, NEG_SLOPE * t1);
            float t2 = xv2[j] + xrv[j]; t2 = fmaxf(t2, NEG_SLOPE * t2);
            float t3 = xv3[j] + xrv[j]; t3 = fmaxf(t3, NEG_SLOPE * t3);
            l0 += t0 * atv[j]; l1 += t1 * atv[j];
            l2 += t2 * atv[j]; l3 += t3 * atv[j];
        }
        #pragma unroll
        for (int off = 1; off < 16; off <<= 1) {
            l0 += __shfl_xor(l0, off, 64);
            l1 += __shfl_xor(l1, off, 64);
            l2 += __shfl_xor(l2, off, 64);
            l3 += __shfl_xor(l3, off, 64);
        }
        if (sub == 0) {
            alpha[(size_t)e0 * NH + head] = l0;
            alpha[(size_t)e1 * NH + head] = l1;
            alpha[(size_t)e2 * NH + head] = l2;
            alpha[(size_t)e3 * NH + head] = l3;
        }
        float bmax = fmaxf(fmaxf(l0, l1), fmaxf(l2, l3));
        if (bmax > mrun) {
            float sc = __expf(mrun - bmax);
            den *= sc;
            #pragma unroll
            for (int j = 0; j < 8; ++j) acc[j] *= sc;
            mrun = bmax;
        }
        float w0 = __expf(l0 - mrun), w1 = __expf(l1 - mrun);
        float w2 = __expf(l2 - mrun), w3 = __expf(l3 - mrun);
        den += (w0 + w1) + (w2 + w3);
        #pragma unroll
        for (int j = 0; j < 8; ++j)
            acc[j] += (w0 * xv0[j] + w1 * xv1[j]) + (w2 * xv2[j] + w3 * xv3[j]);
    }

    for (; k < end; ++k) {
        int src = csr_src[k];
        int eid = csr_eid[k];
        float xv[8];
        ubf8(xlxr + (size_t)src * F2 + foff, xv);
        float s = 0.f;
        #pragma unroll
        for (int j = 0; j < 8; ++j) {
            float t = xv[j] + xrv[j];
            t = fmaxf(t, NEG_SLOPE * t);
            s += t * atv[j];
        }
        #pragma unroll
        for (int off = 1; off < 16; off <<= 1) s += __shfl_xor(s, off, 64);
        if (sub == 0) alpha[(size_t)eid * NH + head] = s;
        if (s > mrun) {
            float sc = __expf(mrun - s);
            den *= sc;
            #pragma unroll
            for (int j = 0; j < 8; ++j) acc[j] *= sc;
            mrun = s;
        }
        float e = __expf(s - mrun);
        den += e;
        #pragma unroll
        for (int j = 0; j < 8; ++j) acc[j] += e * xv[j];
    }

    float inv = 1.f / (den + 1e-16f);

    // head-mean via cross-head shuffles
    float t8[8];
    #pragma unroll
    for (int j = 0; j < 8; ++j) {
        float t = acc[j] * inv;
        t += __shfl_xor(t, 16, 64);
        t += __shfl_xor(t, 32, 64);
        t8[j] = t;
    }
    if (head == 0) {
        float o[8];
        #pragma unroll
        for (int j = 0; j < 8; ++j) {
            int c = sub * 8 + j;
            float s = t8[j] * 0.25f + bias[c];
            float bn = (s - bmn[c]) * rsqrtf(bvr[c] + BN_EPS) * g[c] + be[c];
            o[j] = fmaxf(bn, 0.f);
        }
        if (FINAL) {
            float p = 0.f;
            #pragma unroll
            for (int j = 0; j < 8; ++j) p += o[j] * Wlin[sub * 8 + j];
            p += __shfl_xor(p, 1, 64);
            p += __shfl_xor(p, 2, 64);
            p += __shfl_xor(p, 4, 64);
            p += __shfl_xor(p, 8, 64);
            if (sub == 0) {
                float z = fmaxf(p + blin[0], 0.f);
                out[n] = 1.f / (1.f + __expf(-z));
            }
        } else {
            uint4 ov;
            unsigned w[4];
            #pragma unroll
            for (int q = 0; q < 4; ++q)
                w[q] = (unsigned)f2bf(o[2 * q]) | ((unsigned)f2bf(o[2 * q + 1]) << 16);
            ov.x = w[0]; ov.y = w[1]; ov.z = w[2]; ov.w = w[3];
            *(uint4*)(hout + (size_t)n * HID + sub * 8) = ov;
        }
    }

    // in-kernel alpha finalize: each head-group rewrites its own raw logits
    asm volatile("s_waitcnt vmcnt(0)" ::: "memory");
    for (int k2 = beg + sub; k2 < end; k2 += 16) {
        size_t idx = (size_t)csr_eid[k2] * NH + head;
        alpha[idx] = __expf(alpha[idx] - mrun) * inv;
    }
}

extern "C" void kernel_launch(void* const* d_in, const int* in_sizes, int n_in,
                              void* d_out, int out_size, void* d_ws, size_t ws_size,
                              hipStream_t stream)
{
    const float* x    = (const float*)d_in[0];
    const int*   ei   = (const int*)d_in[1];
    const float* Wl1  = (const float*)d_in[2];
    const float* Wr1  = (const float*)d_in[3];
    const float* att1 = (const float*)d_in[4];
    const float* b1   = (const float*)d_in[5];
    const float* Wl2  = (const float*)d_in[6];
    const float* Wr2  = (const float*)d_in[7];
    const float* att2 = (const float*)d_in[8];
    const float* b2   = (const float*)d_in[9];
    const float* g1   = (const float*)d_in[10];
    const float* be1  = (const float*)d_in[11];
    const float* m1   = (const float*)d_in[12];
    const float* v1   = (const float*)d_in[13];
    const float* g2   = (const float*)d_in[14];
    const float* be2  = (const float*)d_in[15];
    const float* m2   = (const float*)d_in[16];
    const float* v2   = (const float*)d_in[17];
    const float* Wlin = (const float*)d_in[18];
    const float* blin = (const float*)d_in[19];

    const int IN_C = 256;
    const int N = in_sizes[0] / IN_C;       // 10000
    const int E = in_sizes[1] / 2;          // 320000
    const int Etot = E + N;                 // with self loops

    float* out    = (float*)d_out;          // [N]
    float* alpha1 = out + N;                // [Etot*NH]
    float* alpha2 = alpha1 + (size_t)Etot * NH;

    // workspace layout (bytes)
    char* wsb = (char*)d_ws;
    ushort* xbf   = (ushort*)wsb;                       wsb += (size_t)N * IN_C * 2;
    ushort* xlxr  = (ushort*)wsb;                       wsb += (size_t)N * F2 * 2;
    ushort* hbbf  = (ushort*)wsb;                       wsb += (size_t)N * HID * 2;
    ushort* wt1   = (ushort*)wsb;                       wsb += (size_t)F2 * IN_C * 2;  // [1024][256]
    ushort* wt2   = (ushort*)wsb;                       wsb += (size_t)F2 * HID * 2;   // [1024][128]
    int*    deg    = (int*)wsb;                         wsb += (size_t)N * 4;
    int*    cursor = (int*)wsb;                         wsb += (size_t)N * 4;
    int*    rowptr = (int*)wsb;                         wsb += (size_t)(N + 1) * 4;
    int*    csrsrc = (int*)wsb;                         wsb += (size_t)Etot * 4;
    int*    csreid = (int*)wsb;

    dim3 blk(256);
    dim3 gemm_grid((N + 127) / 128, F2 / 128);
    int node_wave_blocks = (N + 3) / 4;
    int etot_blocks = (Etot + 255) / 256;

    // ---- casts (+deg zero) ----
    cast_bf16_deg<<<(N * IN_C / 4 + 255) / 256, blk, 0, stream>>>(x, xbf, N * IN_C, deg, N);
    transpose_cast2<<<dim3(IN_C / 32, FEAT / 32, 2), blk, 0, stream>>>(Wl1, Wr1, wt1, wt1 + (size_t)FEAT * IN_C, IN_C, FEAT);
    transpose_cast2<<<dim3(HID / 32, FEAT / 32, 2), blk, 0, stream>>>(Wl2, Wr2, wt2, wt2 + (size_t)FEAT * HID, HID, FEAT);

    // ---- CSR build (shared by both layers) ----
    csr_count<<<etot_blocks, blk, 0, stream>>>(ei, deg, E, Etot);
    scan_rowptr<<<1, 1024, 0, stream>>>(deg, rowptr, cursor, N);
    csr_fill<<<etot_blocks, blk, 0, stream>>>(ei, cursor, csrsrc, csreid, E, Etot);

    // ================= layer 1 =================
    gemm_bf16<<<gemm_grid, blk, 0, stream>>>(xbf, wt1, xlxr, N, F2, IN_C);
    fused_attn<false><<<node_wave_blocks, blk, 0, stream>>>(xlxr, rowptr, csrsrc, csreid,
                                                            att1, alpha1, b1, g1, be1, m1, v1,
                                                            hbbf, Wlin, blin, out, N);

    // ================= layer 2 =================
    gemm_bf16<<<gemm_grid, blk, 0, stream>>>(hbbf, wt2, xlxr, N, F2, HID);
    fused_attn<true><<<node_wave_blocks, blk, 0, stream>>>(xlxr, rowptr, csrsrc, csreid,
                                                           att2, alpha2, b2, g2, be2, m2, v2,
                                                           hbbf, Wlin, blin, out, N);
}